// Round 8
// baseline (622.895 us; speedup 1.0000x reference)
//
#include <hip/hip_runtime.h>

#define NB 8
#define NC 64
#define NN 4096
#define NO 64
#define KK 20
#define EPSV 1e-5f
#define SLOPE 0.2f

typedef __attribute__((ext_vector_type(8))) short short8x;
typedef __attribute__((ext_vector_type(4))) float float4x;

// ws layout (float words):
// y1   : [B][N][O]            @0         2097152
// y2   : [B][N][O]            @2097152   2097152
// xx   : [B][N]               @4194304   32768
// keyu : [B][N][2][20] u32    @4227072   1310720
// idxu : [B][N][2][20] u16    @5537792   655360 words
// wa   : [C][O]               @6193152   4096
// wb   : [C][O]               @6197248   4096
// xThi : [B][N][C] bf16       @6201344   1048576
// xTmid: [B][N][C] bf16       @7249920   1048576
// xTlo : [B][N][C] bf16       @8298496   1048576

__device__ __forceinline__ unsigned short bfh(float f) {  // fp32 -> bf16 (RNE)
  unsigned u = __float_as_uint(f);
  unsigned r = u + 0x7FFFu + ((u >> 16) & 1u);
  return (unsigned short)(r >> 16);
}

__device__ __forceinline__ unsigned flipf(float f) {
  unsigned u = __float_as_uint(f);
  return u ^ ((unsigned)((int)u >> 31) | 0x80000000u);
}

__global__ void k0_wprep(const float* __restrict__ W,
                         float* __restrict__ wa, float* __restrict__ wb) {
  int t = threadIdx.x;
  for (int i = t; i < NC * NO; i += 256) {
    int o = i & 63, c = i >> 6;
    float w1 = W[o * 128 + c];
    float w2 = W[o * 128 + 64 + c];
    wa[i] = w1 - w2;  // [c][o]
    wb[i] = w2;
  }
}

__global__ __launch_bounds__(256) void k1_feat(const float* __restrict__ x,
    const float* __restrict__ waT, const float* __restrict__ wbT,
    float* __restrict__ y1, float* __restrict__ y2, float* __restrict__ xxg,
    unsigned short* __restrict__ xThi, unsigned short* __restrict__ xTmid,
    unsigned short* __restrict__ xTlo) {
  __shared__ __align__(16) float xs[NC * 68];   // [c][n] stride 68
  __shared__ __align__(16) float wa[NC * NO];
  __shared__ __align__(16) float wb[NC * NO];
  int t = threadIdx.x;
  int b = blockIdx.x >> 6;
  int gr0 = (blockIdx.x & 63) << 6;
  const float* xb = x + (size_t)b * NC * NN;
  #pragma unroll
  for (int k = 0; k < 4; ++k) {
    int i4 = t + k * 256;
    int c = i4 >> 4, col4 = (i4 & 15) << 2;
    *(float4*)&xs[c * 68 + col4] = *(const float4*)&xb[(size_t)c * NN + gr0 + col4];
    *(float4*)&wa[c * 64 + col4] = *(const float4*)&waT[c * 64 + col4];
    *(float4*)&wb[c * 64 + col4] = *(const float4*)&wbT[c * 64 + col4];
  }
  __syncthreads();
  if (t < 64) {
    float s = 0.f;
    #pragma unroll
    for (int c = 0; c < NC; ++c) { float v = xs[c * 68 + t]; s = fmaf(v, v, s); }
    xxg[b * NN + gr0 + t] = s;
  }
  int o = t & 63, w = t >> 6;
  for (int j = 0; j < 16; ++j) {
    int n = j * 4 + w;
    float a1 = 0.f, a2 = 0.f;
    #pragma unroll
    for (int c = 0; c < NC; ++c) {
      float xv = xs[c * 68 + n];
      a1 = fmaf(wa[c * 64 + o], xv, a1);
      a2 = fmaf(wb[c * 64 + o], xv, a2);
    }
    size_t base = ((size_t)b * NN + gr0 + n) * NO + o;
    y1[base] = a1;
    y2[base] = a2;
  }
  // 3-way bf16 split, transposed layout xT[b][n][c]
  int n2 = t >> 2, c0 = (t & 3) << 4;
  short8x vh[2], vm[2], vl[2];
  #pragma unroll
  for (int i = 0; i < 16; ++i) {
    float v = xs[(c0 + i) * 68 + n2];
    unsigned short h = bfh(v);
    float hf = __uint_as_float((unsigned)h << 16);
    float r1 = v - hf;
    unsigned short md = bfh(r1);
    float mf = __uint_as_float((unsigned)md << 16);
    unsigned short lo = bfh(r1 - mf);
    vh[i >> 3][i & 7] = (short)h;
    vm[i >> 3][i & 7] = (short)md;
    vl[i >> 3][i & 7] = (short)lo;
  }
  size_t tb = ((size_t)(b * NN + gr0 + n2)) * 64 + c0;
  *(short8x*)&xThi[tb] = vh[0];  *(short8x*)&xThi[tb + 8] = vh[1];
  *(short8x*)&xTmid[tb] = vm[0]; *(short8x*)&xTmid[tb + 8] = vm[1];
  *(short8x*)&xTlo[tb] = vl[0];  *(short8x*)&xTlo[tb + 8] = vl[1];
}

// ----- MFMA split-bf16 Gram + per-row exact top-K (column half) -----
// grid 1024: blk = b*128 + rowgroup*2 + half; 64-col tiles, high occupancy
__global__ __launch_bounds__(256, 5) void k2_topk(
    const unsigned short* __restrict__ xThi, const unsigned short* __restrict__ xTmid,
    const unsigned short* __restrict__ xTlo, const float* __restrict__ xxg,
    unsigned* __restrict__ keyuG, unsigned short* __restrict__ idxG) {
  __shared__ __align__(16) unsigned short Rb[3 * 4096];  // 24KB B-tiles hi/mid/lo
                                                         // alias: candU u32[64*64]=16KB; M u64[32*84]=21.5KB
  __shared__ __align__(16) float xxs[64];
  __shared__ unsigned cutq[256];                         // [r][q], flipped-u32
  unsigned* candU = (unsigned*)Rb;

  int t = threadIdx.x;
  int blk = blockIdx.x;
  int b = blk >> 7;
  int rem = blk & 127;
  int rg = rem >> 1, half = rem & 1;
  int gr0 = rg << 6;
  int gc0 = half << 11;
  int w = t >> 6;                               // wave: rows 16w..16w+15
  int lm = t & 15;                              // lane&15
  int quad = (t >> 4) & 3;                      // lane>>4
  int orow = t & 63, oq = t >> 6;               // owner (row, quarter)

  // persistent A-fragments (rows gr0+16w+lm, 3 levels x 2 k-steps)
  size_t abase = ((size_t)(b * NN + gr0 + 16 * w + lm)) * 64;
  short8x Ah[2], Am[2], Al[2];
  #pragma unroll
  for (int ks = 0; ks < 2; ++ks) {
    int co = ks * 32 + quad * 8;
    Ah[ks] = *(const short8x*)&xThi[abase + co];
    Am[ks] = *(const short8x*)&xTmid[abase + co];
    Al[ks] = *(const short8x*)&xTlo[abase + co];
  }
  cutq[t] = 0xFFFFFFFFu;

  unsigned long long lst[KK];                   // packed (flip(key)<<12)|m
  #pragma unroll
  for (int j = 0; j < KK; ++j) lst[j] = ~0ull;

  int rotr = orow & 31;                         // per-row word rotation
  size_t bbase = (size_t)(b * NN) * 64;

  for (int mt = 0; mt < 32; ++mt) {
    int gm0 = gc0 + (mt << 6);
    __syncthreads();  // (a) prev cand consumed + prev Rb reads done
    #pragma unroll
    for (int lvl = 0; lvl < 3; ++lvl) {
      const unsigned short* src = (lvl == 0) ? xThi : (lvl == 1) ? xTmid : xTlo;
      unsigned short* dst = Rb + lvl * 4096;
      #pragma unroll
      for (int p = 0; p < 2; ++p) {
        int idx = p * 256 + t;
        int n = idx >> 3, o = idx & 7;
        *(short8x*)&dst[n * 64 + ((o + n) & 7) * 8] =
            *(const short8x*)&src[bbase + (size_t)(gm0 + n) * 64 + o * 8];
      }
    }
    if (t < 16) *(float4*)&xxs[t * 4] = *(const float4*)&xxg[b * NN + gm0 + t * 4];
    __syncthreads();  // (b) Rb ready

    float4x acc[4];
    #pragma unroll
    for (int j = 0; j < 4; ++j) acc[j] = (float4x){0.f, 0.f, 0.f, 0.f};

    const unsigned short* RbH = Rb;
    const unsigned short* RbM = Rb + 4096;
    const unsigned short* RbL = Rb + 8192;
    #pragma unroll
    for (int ks = 0; ks < 2; ++ks) {
      #pragma unroll
      for (int j = 0; j < 4; ++j) {
        int n = 16 * j + lm;
        int off = n * 64 + ((ks * 4 + quad + n) & 7) * 8;
        short8x bh = *(const short8x*)&RbH[off];
        short8x bm = *(const short8x*)&RbM[off];
        short8x bl = *(const short8x*)&RbL[off];
        acc[j] = __builtin_amdgcn_mfma_f32_16x16x32_bf16(Am[ks], bm, acc[j], 0, 0, 0);
        acc[j] = __builtin_amdgcn_mfma_f32_16x16x32_bf16(Ah[ks], bl, acc[j], 0, 0, 0);
        acc[j] = __builtin_amdgcn_mfma_f32_16x16x32_bf16(Al[ks], bh, acc[j], 0, 0, 0);
        acc[j] = __builtin_amdgcn_mfma_f32_16x16x32_bf16(Ah[ks], bm, acc[j], 0, 0, 0);
        acc[j] = __builtin_amdgcn_mfma_f32_16x16x32_bf16(Am[ks], bh, acc[j], 0, 0, 0);
        acc[j] = __builtin_amdgcn_mfma_f32_16x16x32_bf16(Ah[ks], bh, acc[j], 0, 0, 0);
      }
    }

    float xq[4];
    #pragma unroll
    for (int j = 0; j < 4; ++j) xq[j] = xxs[16 * j + lm];

    __syncthreads();  // (c) Rb reads done -> overwrite as candU

    // keys: xx[m] - 2*G; D layout: col=16j+lm, row=quad*4+q (+16w)
    #pragma unroll
    for (int j = 0; j < 4; ++j) {
      int c = 16 * j + lm;
      #pragma unroll
      for (int q = 0; q < 4; ++q) {
        int rl = quad * 4 + q;
        int r = 16 * w + rl;
        float key = fmaf(-2.f, acc[j][q], xq[j]);
        int pos = (c & 32) | ((c + (r & 31)) & 31);
        candU[r * 64 + pos] = flipf(key);
      }
    }
    __syncthreads();  // (d) cand ready

    // owner scan: 16 cols, conflict-free b32 reads, mask+ctz inserts
    unsigned rc0 = cutq[orow * 4 + 0], rc1 = cutq[orow * 4 + 1];
    unsigned rc2 = cutq[orow * 4 + 2], rc3 = cutq[orow * 4 + 3];
    unsigned thr = min(min(rc0, rc1), min(rc2, rc3));
    unsigned own19 = (unsigned)(lst[KK - 1] >> 12);
    thr = min(thr, own19);
    unsigned mask = 0;
    #pragma unroll
    for (int g = 0; g < 16; ++g) {
      int c = oq * 16 + g;
      int pos = (c & 32) | ((c + rotr) & 31);
      unsigned ku = candU[orow * 64 + pos];
      mask |= (unsigned)(ku <= thr) << g;
    }
    while (mask) {
      int e = __builtin_ctz(mask);
      mask &= mask - 1;
      int c = oq * 16 + e;
      int pos = (c & 32) | ((c + rotr) & 31);
      unsigned ku = candU[orow * 64 + pos];
      unsigned long long p = ((unsigned long long)ku << 12) | (unsigned)(gm0 + c);
      if (p < lst[KK - 1]) {
        #pragma unroll
        for (int j = KK - 1; j >= 1; --j) {
          bool sh = p < lst[j - 1];
          unsigned long long cur = (p < lst[j]) ? p : lst[j];
          lst[j] = sh ? lst[j - 1] : cur;
        }
        if (p < lst[0]) lst[0] = p;
      }
    }
    cutq[orow * 4 + oq] = (unsigned)(lst[KK - 1] >> 12);  // monotone benign race
  }

  // two-phase merge (rows 0-31, then 32-63): M = u64[32][84] aliases Rb
  unsigned long long* M = (unsigned long long*)Rb;
  #pragma unroll 1
  for (int ph = 0; ph < 2; ++ph) {
    __syncthreads();
    if ((orow >> 5) == ph) {
      int r5 = orow & 31;
      #pragma unroll
      for (int k = 0; k < KK; ++k) M[r5 * 84 + oq * 21 + k] = lst[k];
      M[r5 * 84 + oq * 21 + KK] = ~0ull;
    }
    __syncthreads();
    if (t < 32) {
      int h0 = 0, h1 = 0, h2 = 0, h3 = 0;
      int rb = t * 84;
      int row = ph * 32 + t;
      size_t base = ((size_t)(b * NN + gr0 + row) * 2 + half) * KK;
      for (int k = 0; k < KK; ++k) {
        unsigned long long v0 = M[rb + h0];
        unsigned long long v1 = M[rb + 21 + h1];
        unsigned long long v2 = M[rb + 42 + h2];
        unsigned long long v3 = M[rb + 63 + h3];
        unsigned long long bv = v0; int bq = 0;
        if (v1 < bv) { bv = v1; bq = 1; }
        if (v2 < bv) { bv = v2; bq = 2; }
        if (v3 < bv) { bv = v3; bq = 3; }
        keyuG[base + k] = (unsigned)(bv >> 12);
        idxG[base + k] = (unsigned short)(bv & 0xFFFu);
        if (bq == 0) h0++; else if (bq == 1) h1++; else if (bq == 2) h2++; else h3++;
      }
    }
  }
}

__global__ __launch_bounds__(256) void k3_out(const float* __restrict__ y1,
    const float* __restrict__ y2, const unsigned* __restrict__ keyuG,
    const unsigned short* __restrict__ idxG,
    const float* __restrict__ gamma, const float* __restrict__ beta,
    const float* __restrict__ rmean, const float* __restrict__ rvar,
    float* __restrict__ out) {
  __shared__ int sidx[64 * KK];
  __shared__ float ot[64 * 65];  // [o][n], pad 65
  int t = threadIdx.x;
  int b = blockIdx.x >> 6;
  int gr0 = (blockIdx.x & 63) << 6;
  if (t < 64) {  // 2-way merge of column-half lists
    size_t base0 = ((size_t)(b * NN + gr0 + t) * 2) * KK;
    size_t base1 = base0 + KK;
    int h0 = 0, h1 = 0;
    for (int k = 0; k < KK; ++k) {
      int a0 = h0 < KK ? h0 : KK - 1;
      int a1 = h1 < KK ? h1 : KK - 1;
      unsigned k0v = keyuG[base0 + a0]; unsigned i0 = idxG[base0 + a0];
      unsigned k1v = keyuG[base1 + a1]; unsigned i1 = idxG[base1 + a1];
      bool take0 = (h1 >= KK) ||
                   ((h0 < KK) && (k0v < k1v || (k0v == k1v && i0 < i1)));
      sidx[t * KK + k] = take0 ? (int)i0 : (int)i1;
      if (take0) h0++; else h1++;
    }
  }
  int l = t & 63, w = t >> 6;
  float sc = gamma[l] * rsqrtf(rvar[l] + EPSV);
  float tt = fmaf(-rmean[l], sc, beta[l]);
  __syncthreads();
  const float* y2b = y2 + (size_t)b * NN * NO;
  for (int rr = 0; rr < 16; ++rr) {
    int row = w * 16 + rr;
    float v1 = y1[((size_t)b * NN + gr0 + row) * NO + l];
    int mk[KK];
    #pragma unroll
    for (int k = 0; k < KK; ++k) mk[k] = sidx[row * KK + k];
    float vv[KK];
    #pragma unroll
    for (int k = 0; k < KK; ++k) vv[k] = y2b[(size_t)mk[k] * NO + l];  // 20 in flight
    float best = -3.4e38f;
    #pragma unroll
    for (int k = 0; k < KK; ++k) {
      float v = v1 + vv[k];
      v = fmaf(v, sc, tt);
      v = v >= 0.f ? v : SLOPE * v;
      best = fmaxf(best, v);
    }
    ot[l * 65 + row] = best;
  }
  __syncthreads();
  float* ob = out + (size_t)b * NO * NN;
  for (int i = t; i < 4096; i += 256) {
    int o = i >> 6, n = i & 63;
    ob[(size_t)o * NN + gr0 + n] = ot[o * 65 + n];  // coalesced
  }
}

extern "C" void kernel_launch(void* const* d_in, const int* in_sizes, int n_in,
                              void* d_out, int out_size, void* d_ws, size_t ws_size,
                              hipStream_t stream) {
  const float* x     = (const float*)d_in[0];
  const float* W     = (const float*)d_in[1];
  const float* gamma = (const float*)d_in[2];
  const float* beta  = (const float*)d_in[3];
  const float* rmean = (const float*)d_in[4];
  const float* rvar  = (const float*)d_in[5];
  float* ws  = (float*)d_ws;
  float* y1    = ws;
  float* y2    = ws + 2097152;
  float* xx    = ws + 4194304;
  unsigned* keyu = (unsigned*)(ws + 4227072);
  unsigned short* idxu = (unsigned short*)(ws + 5537792);
  float* wa    = ws + 6193152;
  float* wb    = ws + 6197248;
  unsigned short* xThi  = (unsigned short*)(ws + 6201344);
  unsigned short* xTmid = (unsigned short*)(ws + 7249920);
  unsigned short* xTlo  = (unsigned short*)(ws + 8298496);
  float* out = (float*)d_out;

  hipLaunchKernelGGL(k0_wprep, dim3(1),    dim3(256), 0, stream, W, wa, wb);
  hipLaunchKernelGGL(k1_feat,  dim3(512),  dim3(256), 0, stream, x, wa, wb, y1, y2, xx,
                     xThi, xTmid, xTlo);
  hipLaunchKernelGGL(k2_topk,  dim3(1024), dim3(256), 0, stream, xThi, xTmid, xTlo,
                     xx, keyu, idxu);
  hipLaunchKernelGGL(k3_out,   dim3(512),  dim3(256), 0, stream, y1, y2, keyu, idxu,
                     gamma, beta, rmean, rvar, out);
}

// Round 9
// 604.418 us; speedup vs baseline: 1.0306x; 1.0306x over previous
//
#include <hip/hip_runtime.h>

#define NB 8
#define NC 64
#define NN 4096
#define NO 64
#define KK 20
#define EPSV 1e-5f
#define SLOPE 0.2f

typedef __attribute__((ext_vector_type(8))) short short8x;
typedef __attribute__((ext_vector_type(4))) float float4x;

// ws layout (float words):
// y1   : [B][N][O]            @0         2097152
// y2   : [B][N][O]            @2097152   2097152
// xx   : [B][N]               @4194304   32768
// keyu : [B][N][2][20] u32    @4227072   1310720
// idxu : [B][N][2][20] u16    @5537792   655360 words
// wa   : [C][O]               @6193152   4096
// wb   : [C][O]               @6197248   4096
// xThi : [B][N][C] bf16       @6201344   1048576
// xTmid: [B][N][C] bf16       @7249920   1048576
// xTlo : [B][N][C] bf16       @8298496   1048576

__device__ __forceinline__ unsigned short bfh(float f) {  // fp32 -> bf16 (RNE)
  unsigned u = __float_as_uint(f);
  unsigned r = u + 0x7FFFu + ((u >> 16) & 1u);
  return (unsigned short)(r >> 16);
}

__device__ __forceinline__ unsigned flipf(float f) {
  unsigned u = __float_as_uint(f);
  return u ^ ((unsigned)((int)u >> 31) | 0x80000000u);
}

__global__ void k0_wprep(const float* __restrict__ W,
                         float* __restrict__ wa, float* __restrict__ wb) {
  int t = threadIdx.x;
  for (int i = t; i < NC * NO; i += 256) {
    int o = i & 63, c = i >> 6;
    float w1 = W[o * 128 + c];
    float w2 = W[o * 128 + 64 + c];
    wa[i] = w1 - w2;  // [c][o]
    wb[i] = w2;
  }
}

__global__ __launch_bounds__(256) void k1_feat(const float* __restrict__ x,
    const float* __restrict__ waT, const float* __restrict__ wbT,
    float* __restrict__ y1, float* __restrict__ y2, float* __restrict__ xxg,
    unsigned short* __restrict__ xThi, unsigned short* __restrict__ xTmid,
    unsigned short* __restrict__ xTlo) {
  __shared__ __align__(16) float xs[NC * 68];   // [c][n] stride 68
  __shared__ __align__(16) float wa[NC * NO];
  __shared__ __align__(16) float wb[NC * NO];
  int t = threadIdx.x;
  int b = blockIdx.x >> 6;
  int gr0 = (blockIdx.x & 63) << 6;
  const float* xb = x + (size_t)b * NC * NN;
  #pragma unroll
  for (int k = 0; k < 4; ++k) {
    int i4 = t + k * 256;
    int c = i4 >> 4, col4 = (i4 & 15) << 2;
    *(float4*)&xs[c * 68 + col4] = *(const float4*)&xb[(size_t)c * NN + gr0 + col4];
    *(float4*)&wa[c * 64 + col4] = *(const float4*)&waT[c * 64 + col4];
    *(float4*)&wb[c * 64 + col4] = *(const float4*)&wbT[c * 64 + col4];
  }
  __syncthreads();
  if (t < 64) {
    float s = 0.f;
    #pragma unroll
    for (int c = 0; c < NC; ++c) { float v = xs[c * 68 + t]; s = fmaf(v, v, s); }
    xxg[b * NN + gr0 + t] = s;
  }
  int o = t & 63, w = t >> 6;
  for (int j = 0; j < 16; ++j) {
    int n = j * 4 + w;
    float a1 = 0.f, a2 = 0.f;
    #pragma unroll
    for (int c = 0; c < NC; ++c) {
      float xv = xs[c * 68 + n];
      a1 = fmaf(wa[c * 64 + o], xv, a1);
      a2 = fmaf(wb[c * 64 + o], xv, a2);
    }
    size_t base = ((size_t)b * NN + gr0 + n) * NO + o;
    y1[base] = a1;
    y2[base] = a2;
  }
  // 3-way bf16 split, transposed layout xT[b][n][c]
  int n2 = t >> 2, c0 = (t & 3) << 4;
  short8x vh[2], vm[2], vl[2];
  #pragma unroll
  for (int i = 0; i < 16; ++i) {
    float v = xs[(c0 + i) * 68 + n2];
    unsigned short h = bfh(v);
    float hf = __uint_as_float((unsigned)h << 16);
    float r1 = v - hf;
    unsigned short md = bfh(r1);
    float mf = __uint_as_float((unsigned)md << 16);
    unsigned short lo = bfh(r1 - mf);
    vh[i >> 3][i & 7] = (short)h;
    vm[i >> 3][i & 7] = (short)md;
    vl[i >> 3][i & 7] = (short)lo;
  }
  size_t tb = ((size_t)(b * NN + gr0 + n2)) * 64 + c0;
  *(short8x*)&xThi[tb] = vh[0];  *(short8x*)&xThi[tb + 8] = vh[1];
  *(short8x*)&xTmid[tb] = vm[0]; *(short8x*)&xTmid[tb + 8] = vm[1];
  *(short8x*)&xTlo[tb] = vl[0];  *(short8x*)&xTlo[tb + 8] = vl[1];
}

// ----- MFMA split-bf16 Gram + per-row exact top-K (column half) -----
// grid 1024: blk = (rowgroup*2 + half)*8 + b  => batch-per-XCD locality
// (blockIdx % 8 == XCD round-robin [m09]; all 128 blocks of batch b share one
//  XCD whose 1.5MB xT stream fits the 4MB per-XCD L2 -> re-reads hit L2)
__global__ __launch_bounds__(256, 5) void k2_topk(
    const unsigned short* __restrict__ xThi, const unsigned short* __restrict__ xTmid,
    const unsigned short* __restrict__ xTlo, const float* __restrict__ xxg,
    unsigned* __restrict__ keyuG, unsigned short* __restrict__ idxG) {
  __shared__ __align__(16) unsigned short Rb[3 * 4096];  // 24KB B-tiles hi/mid/lo
                                                         // alias: candU u32[64*64]=16KB; M u64[32*84]=21.5KB
  __shared__ __align__(16) float xxs[64];
  __shared__ unsigned cutq[256];                         // [r][q], flipped-u32
  unsigned* candU = (unsigned*)Rb;

  int t = threadIdx.x;
  int blk = blockIdx.x;
  int b = blk & 7;                              // batch -> XCD (locality swizzle)
  int rem = blk >> 3;
  int rg = rem >> 1, half = rem & 1;
  int gr0 = rg << 6;
  int gc0 = half << 11;
  int w = t >> 6;                               // wave: rows 16w..16w+15
  int lm = t & 15;                              // lane&15
  int quad = (t >> 4) & 3;                      // lane>>4
  int orow = t & 63, oq = t >> 6;               // owner (row, quarter)

  // persistent A-fragments (rows gr0+16w+lm, 3 levels x 2 k-steps)
  size_t abase = ((size_t)(b * NN + gr0 + 16 * w + lm)) * 64;
  short8x Ah[2], Am[2], Al[2];
  #pragma unroll
  for (int ks = 0; ks < 2; ++ks) {
    int co = ks * 32 + quad * 8;
    Ah[ks] = *(const short8x*)&xThi[abase + co];
    Am[ks] = *(const short8x*)&xTmid[abase + co];
    Al[ks] = *(const short8x*)&xTlo[abase + co];
  }
  cutq[t] = 0xFFFFFFFFu;

  unsigned long long lst[KK];                   // packed (flip(key)<<12)|m
  #pragma unroll
  for (int j = 0; j < KK; ++j) lst[j] = ~0ull;

  int rotr = orow & 31;                         // per-row word rotation
  size_t bbase = (size_t)(b * NN) * 64;

  for (int mt = 0; mt < 32; ++mt) {
    int gm0 = gc0 + (mt << 6);
    __syncthreads();  // (a) prev cand consumed + prev Rb reads done
    #pragma unroll
    for (int lvl = 0; lvl < 3; ++lvl) {
      const unsigned short* src = (lvl == 0) ? xThi : (lvl == 1) ? xTmid : xTlo;
      unsigned short* dst = Rb + lvl * 4096;
      #pragma unroll
      for (int p = 0; p < 2; ++p) {
        int idx = p * 256 + t;
        int n = idx >> 3, o = idx & 7;
        *(short8x*)&dst[n * 64 + ((o + n) & 7) * 8] =
            *(const short8x*)&src[bbase + (size_t)(gm0 + n) * 64 + o * 8];
      }
    }
    if (t < 16) *(float4*)&xxs[t * 4] = *(const float4*)&xxg[b * NN + gm0 + t * 4];
    __syncthreads();  // (b) Rb ready

    float4x acc[4];
    #pragma unroll
    for (int j = 0; j < 4; ++j) acc[j] = (float4x){0.f, 0.f, 0.f, 0.f};

    const unsigned short* RbH = Rb;
    const unsigned short* RbM = Rb + 4096;
    const unsigned short* RbL = Rb + 8192;
    #pragma unroll
    for (int ks = 0; ks < 2; ++ks) {
      #pragma unroll
      for (int j = 0; j < 4; ++j) {
        int n = 16 * j + lm;
        int off = n * 64 + ((ks * 4 + quad + n) & 7) * 8;
        short8x bh = *(const short8x*)&RbH[off];
        short8x bm = *(const short8x*)&RbM[off];
        short8x bl = *(const short8x*)&RbL[off];
        acc[j] = __builtin_amdgcn_mfma_f32_16x16x32_bf16(Am[ks], bm, acc[j], 0, 0, 0);
        acc[j] = __builtin_amdgcn_mfma_f32_16x16x32_bf16(Ah[ks], bl, acc[j], 0, 0, 0);
        acc[j] = __builtin_amdgcn_mfma_f32_16x16x32_bf16(Al[ks], bh, acc[j], 0, 0, 0);
        acc[j] = __builtin_amdgcn_mfma_f32_16x16x32_bf16(Ah[ks], bm, acc[j], 0, 0, 0);
        acc[j] = __builtin_amdgcn_mfma_f32_16x16x32_bf16(Am[ks], bh, acc[j], 0, 0, 0);
        acc[j] = __builtin_amdgcn_mfma_f32_16x16x32_bf16(Ah[ks], bh, acc[j], 0, 0, 0);
      }
    }

    float xq[4];
    #pragma unroll
    for (int j = 0; j < 4; ++j) xq[j] = xxs[16 * j + lm];

    __syncthreads();  // (c) Rb reads done -> overwrite as candU

    // keys: xx[m] - 2*G; D layout: col=16j+lm, row=quad*4+q (+16w)
    #pragma unroll
    for (int j = 0; j < 4; ++j) {
      int c = 16 * j + lm;
      #pragma unroll
      for (int q = 0; q < 4; ++q) {
        int rl = quad * 4 + q;
        int r = 16 * w + rl;
        float key = fmaf(-2.f, acc[j][q], xq[j]);
        int pos = (c & 32) | ((c + (r & 31)) & 31);
        candU[r * 64 + pos] = flipf(key);
      }
    }
    __syncthreads();  // (d) cand ready

    // owner scan: 16 cols, conflict-free b32 reads, mask+ctz inserts
    unsigned rc0 = cutq[orow * 4 + 0], rc1 = cutq[orow * 4 + 1];
    unsigned rc2 = cutq[orow * 4 + 2], rc3 = cutq[orow * 4 + 3];
    unsigned thr = min(min(rc0, rc1), min(rc2, rc3));
    unsigned own19 = (unsigned)(lst[KK - 1] >> 12);
    thr = min(thr, own19);
    unsigned mask = 0;
    #pragma unroll
    for (int g = 0; g < 16; ++g) {
      int c = oq * 16 + g;
      int pos = (c & 32) | ((c + rotr) & 31);
      unsigned ku = candU[orow * 64 + pos];
      mask |= (unsigned)(ku <= thr) << g;
    }
    while (mask) {
      int e = __builtin_ctz(mask);
      mask &= mask - 1;
      int c = oq * 16 + e;
      int pos = (c & 32) | ((c + rotr) & 31);
      unsigned ku = candU[orow * 64 + pos];
      unsigned long long p = ((unsigned long long)ku << 12) | (unsigned)(gm0 + c);
      if (p < lst[KK - 1]) {
        #pragma unroll
        for (int j = KK - 1; j >= 1; --j) {
          bool sh = p < lst[j - 1];
          unsigned long long cur = (p < lst[j]) ? p : lst[j];
          lst[j] = sh ? lst[j - 1] : cur;
        }
        if (p < lst[0]) lst[0] = p;
      }
    }
    cutq[orow * 4 + oq] = (unsigned)(lst[KK - 1] >> 12);  // monotone benign race
  }

  // two-phase merge (rows 0-31, then 32-63): M = u64[32][84] aliases Rb
  unsigned long long* M = (unsigned long long*)Rb;
  #pragma unroll 1
  for (int ph = 0; ph < 2; ++ph) {
    __syncthreads();
    if ((orow >> 5) == ph) {
      int r5 = orow & 31;
      #pragma unroll
      for (int k = 0; k < KK; ++k) M[r5 * 84 + oq * 21 + k] = lst[k];
      M[r5 * 84 + oq * 21 + KK] = ~0ull;
    }
    __syncthreads();
    if (t < 32) {
      int h0 = 0, h1 = 0, h2 = 0, h3 = 0;
      int rb = t * 84;
      int row = ph * 32 + t;
      size_t base = ((size_t)(b * NN + gr0 + row) * 2 + half) * KK;
      for (int k = 0; k < KK; ++k) {
        unsigned long long v0 = M[rb + h0];
        unsigned long long v1 = M[rb + 21 + h1];
        unsigned long long v2 = M[rb + 42 + h2];
        unsigned long long v3 = M[rb + 63 + h3];
        unsigned long long bv = v0; int bq = 0;
        if (v1 < bv) { bv = v1; bq = 1; }
        if (v2 < bv) { bv = v2; bq = 2; }
        if (v3 < bv) { bv = v3; bq = 3; }
        keyuG[base + k] = (unsigned)(bv >> 12);
        idxG[base + k] = (unsigned short)(bv & 0xFFFu);
        if (bq == 0) h0++; else if (bq == 1) h1++; else if (bq == 2) h2++; else h3++;
      }
    }
  }
}

__global__ __launch_bounds__(256) void k3_out(const float* __restrict__ y1,
    const float* __restrict__ y2, const unsigned* __restrict__ keyuG,
    const unsigned short* __restrict__ idxG,
    const float* __restrict__ gamma, const float* __restrict__ beta,
    const float* __restrict__ rmean, const float* __restrict__ rvar,
    float* __restrict__ out) {
  __shared__ int sidx[64 * KK];
  __shared__ float ot[64 * 65];  // [o][n], pad 65
  int t = threadIdx.x;
  int b = blockIdx.x >> 6;
  int gr0 = (blockIdx.x & 63) << 6;
  if (t < 64) {  // 2-way merge of column-half lists
    size_t base0 = ((size_t)(b * NN + gr0 + t) * 2) * KK;
    size_t base1 = base0 + KK;
    int h0 = 0, h1 = 0;
    for (int k = 0; k < KK; ++k) {
      int a0 = h0 < KK ? h0 : KK - 1;
      int a1 = h1 < KK ? h1 : KK - 1;
      unsigned k0v = keyuG[base0 + a0]; unsigned i0 = idxG[base0 + a0];
      unsigned k1v = keyuG[base1 + a1]; unsigned i1 = idxG[base1 + a1];
      bool take0 = (h1 >= KK) ||
                   ((h0 < KK) && (k0v < k1v || (k0v == k1v && i0 < i1)));
      sidx[t * KK + k] = take0 ? (int)i0 : (int)i1;
      if (take0) h0++; else h1++;
    }
  }
  int l = t & 63, w = t >> 6;
  float sc = gamma[l] * rsqrtf(rvar[l] + EPSV);
  float tt = fmaf(-rmean[l], sc, beta[l]);
  __syncthreads();
  const float* y2b = y2 + (size_t)b * NN * NO;
  for (int rr = 0; rr < 16; ++rr) {
    int row = w * 16 + rr;
    float v1 = y1[((size_t)b * NN + gr0 + row) * NO + l];
    int mk[KK];
    #pragma unroll
    for (int k = 0; k < KK; ++k) mk[k] = sidx[row * KK + k];
    float vv[KK];
    #pragma unroll
    for (int k = 0; k < KK; ++k) vv[k] = y2b[(size_t)mk[k] * NO + l];  // 20 in flight
    float best = -3.4e38f;
    #pragma unroll
    for (int k = 0; k < KK; ++k) {
      float v = v1 + vv[k];
      v = fmaf(v, sc, tt);
      v = v >= 0.f ? v : SLOPE * v;
      best = fmaxf(best, v);
    }
    ot[l * 65 + row] = best;
  }
  __syncthreads();
  float* ob = out + (size_t)b * NO * NN;
  for (int i = t; i < 4096; i += 256) {
    int o = i >> 6, n = i & 63;
    ob[(size_t)o * NN + gr0 + n] = ot[o * 65 + n];  // coalesced
  }
}

extern "C" void kernel_launch(void* const* d_in, const int* in_sizes, int n_in,
                              void* d_out, int out_size, void* d_ws, size_t ws_size,
                              hipStream_t stream) {
  const float* x     = (const float*)d_in[0];
  const float* W     = (const float*)d_in[1];
  const float* gamma = (const float*)d_in[2];
  const float* beta  = (const float*)d_in[3];
  const float* rmean = (const float*)d_in[4];
  const float* rvar  = (const float*)d_in[5];
  float* ws  = (float*)d_ws;
  float* y1    = ws;
  float* y2    = ws + 2097152;
  float* xx    = ws + 4194304;
  unsigned* keyu = (unsigned*)(ws + 4227072);
  unsigned short* idxu = (unsigned short*)(ws + 5537792);
  float* wa    = ws + 6193152;
  float* wb    = ws + 6197248;
  unsigned short* xThi  = (unsigned short*)(ws + 6201344);
  unsigned short* xTmid = (unsigned short*)(ws + 7249920);
  unsigned short* xTlo  = (unsigned short*)(ws + 8298496);
  float* out = (float*)d_out;

  hipLaunchKernelGGL(k0_wprep, dim3(1),    dim3(256), 0, stream, W, wa, wb);
  hipLaunchKernelGGL(k1_feat,  dim3(512),  dim3(256), 0, stream, x, wa, wb, y1, y2, xx,
                     xThi, xTmid, xTlo);
  hipLaunchKernelGGL(k2_topk,  dim3(1024), dim3(256), 0, stream, xThi, xTmid, xTlo,
                     xx, keyu, idxu);
  hipLaunchKernelGGL(k3_out,   dim3(512),  dim3(256), 0, stream, y1, y2, keyu, idxu,
                     gamma, beta, rmean, rvar, out);
}

// Round 11
// 403.656 us; speedup vs baseline: 1.5431x; 1.4974x over previous
//
#include <hip/hip_runtime.h>

#define NB 8
#define NC 64
#define NN 4096
#define NO 64
#define KK 20
#define EPSV 1e-5f
#define SLOPE 0.2f

typedef __attribute__((ext_vector_type(8))) short short8x;
typedef __attribute__((ext_vector_type(4))) float float4x;

// ws layout (float words):
// y1   : [B][N][O]            @0         2097152
// y2   : [B][N][O]            @2097152   2097152
// xx   : [B][N]               @4194304   32768
// keyu : [B][N][2][20] u32    @4227072   1310720
// idxu : [B][N][2][20] u16    @5537792   655360 words
// wa   : [C][O]               @6193152   4096
// wb   : [C][O]               @6197248   4096
// xThi : [B][N][C] bf16       @6201344   1048576
// xTmid: [B][N][C] bf16       @7249920   1048576
// xTlo : [B][N][C] bf16       @8298496   1048576

__device__ __forceinline__ unsigned short bfh(float f) {  // fp32 -> bf16 (RNE)
  unsigned u = __float_as_uint(f);
  unsigned r = u + 0x7FFFu + ((u >> 16) & 1u);
  return (unsigned short)(r >> 16);
}

__device__ __forceinline__ unsigned flipf(float f) {
  unsigned u = __float_as_uint(f);
  return u ^ ((unsigned)((int)u >> 31) | 0x80000000u);
}

__global__ void k0_wprep(const float* __restrict__ W,
                         float* __restrict__ wa, float* __restrict__ wb) {
  int t = threadIdx.x;
  for (int i = t; i < NC * NO; i += 256) {
    int o = i & 63, c = i >> 6;
    float w1 = W[o * 128 + c];
    float w2 = W[o * 128 + 64 + c];
    wa[i] = w1 - w2;  // [c][o]
    wb[i] = w2;
  }
}

__global__ __launch_bounds__(256) void k1_feat(const float* __restrict__ x,
    const float* __restrict__ waT, const float* __restrict__ wbT,
    float* __restrict__ y1, float* __restrict__ y2, float* __restrict__ xxg,
    unsigned short* __restrict__ xThi, unsigned short* __restrict__ xTmid,
    unsigned short* __restrict__ xTlo) {
  __shared__ __align__(16) float xs[NC * 68];   // [c][n] stride 68
  __shared__ __align__(16) float wa[NC * NO];
  __shared__ __align__(16) float wb[NC * NO];
  int t = threadIdx.x;
  int b = blockIdx.x >> 6;
  int gr0 = (blockIdx.x & 63) << 6;
  const float* xb = x + (size_t)b * NC * NN;
  #pragma unroll
  for (int k = 0; k < 4; ++k) {
    int i4 = t + k * 256;
    int c = i4 >> 4, col4 = (i4 & 15) << 2;
    *(float4*)&xs[c * 68 + col4] = *(const float4*)&xb[(size_t)c * NN + gr0 + col4];
    *(float4*)&wa[c * 64 + col4] = *(const float4*)&waT[c * 64 + col4];
    *(float4*)&wb[c * 64 + col4] = *(const float4*)&wbT[c * 64 + col4];
  }
  __syncthreads();
  if (t < 64) {
    float s = 0.f;
    #pragma unroll
    for (int c = 0; c < NC; ++c) { float v = xs[c * 68 + t]; s = fmaf(v, v, s); }
    xxg[b * NN + gr0 + t] = s;
  }
  int o = t & 63, w = t >> 6;
  for (int j = 0; j < 16; ++j) {
    int n = j * 4 + w;
    float a1 = 0.f, a2 = 0.f;
    #pragma unroll
    for (int c = 0; c < NC; ++c) {
      float xv = xs[c * 68 + n];
      a1 = fmaf(wa[c * 64 + o], xv, a1);
      a2 = fmaf(wb[c * 64 + o], xv, a2);
    }
    size_t base = ((size_t)b * NN + gr0 + n) * NO + o;
    y1[base] = a1;
    y2[base] = a2;
  }
  // 3-level bf16 split (REQUIRED: 2-level flips top-K selections, R10 failed),
  // transposed layout xT[b][n][c]
  int n2 = t >> 2, c0 = (t & 3) << 4;
  short8x vh[2], vm[2], vl[2];
  #pragma unroll
  for (int i = 0; i < 16; ++i) {
    float v = xs[(c0 + i) * 68 + n2];
    unsigned short h = bfh(v);
    float hf = __uint_as_float((unsigned)h << 16);
    float r1 = v - hf;
    unsigned short md = bfh(r1);
    float mf = __uint_as_float((unsigned)md << 16);
    unsigned short lo = bfh(r1 - mf);
    vh[i >> 3][i & 7] = (short)h;
    vm[i >> 3][i & 7] = (short)md;
    vl[i >> 3][i & 7] = (short)lo;
  }
  size_t tb = ((size_t)(b * NN + gr0 + n2)) * 64 + c0;
  *(short8x*)&xThi[tb] = vh[0];  *(short8x*)&xThi[tb + 8] = vh[1];
  *(short8x*)&xTmid[tb] = vm[0]; *(short8x*)&xTmid[tb + 8] = vm[1];
  *(short8x*)&xTlo[tb] = vl[0];  *(short8x*)&xTlo[tb + 8] = vl[1];
}

// ----- MFMA split-bf16 Gram + per-row exact top-K (column half) -----
// grid 1024: blk = b*128 + rowgroup*2 + half (R7-proven ordering, 34MB fetch)
// __launch_bounds__(256,3): cap ~170 VGPR -- lst[20] u64 MUST stay in regs
// (R8/R9 lesson: (256,5) cap 102 spilled lst to scratch -> 0.8GB HBM traffic)
__global__ __launch_bounds__(256, 3) void k2_topk(
    const unsigned short* __restrict__ xThi, const unsigned short* __restrict__ xTmid,
    const unsigned short* __restrict__ xTlo, const float* __restrict__ xxg,
    unsigned* __restrict__ keyuG, unsigned short* __restrict__ idxG) {
  __shared__ __align__(16) unsigned short Rb[3 * 4096];  // 24KB staging hi/mid/lo
                                                         // alias: candU u32 16KB; M u64[32*84]=21.5KB
  __shared__ __align__(16) float xxs[64];
  __shared__ unsigned cutq[256];                         // [r][q], flipped-u32
  unsigned* candU = (unsigned*)Rb;

  int t = threadIdx.x;
  int blk = blockIdx.x;
  int b = blk >> 7;
  int rem = blk & 127;
  int rg = rem >> 1, half = rem & 1;
  int gr0 = rg << 6;
  int gc0 = half << 11;
  int w = t >> 6;                               // wave: rows 16w..16w+15
  int lm = t & 15;                              // lane&15
  int quad = (t >> 4) & 3;                      // lane>>4
  int orow = t & 63, oq = t >> 6;               // owner (row, quarter)

  // persistent A-fragments (rows gr0+16w+lm, 3 levels x 2 k-steps)
  size_t abase = ((size_t)(b * NN + gr0 + 16 * w + lm)) * 64;
  short8x Ah[2], Am[2], Al[2];
  #pragma unroll
  for (int ks = 0; ks < 2; ++ks) {
    int co = ks * 32 + quad * 8;
    Ah[ks] = *(const short8x*)&xThi[abase + co];
    Am[ks] = *(const short8x*)&xTmid[abase + co];
    Al[ks] = *(const short8x*)&xTlo[abase + co];
  }
  cutq[t] = 0xFFFFFFFFu;

  unsigned long long lst[KK];                   // packed (flip(key)<<12)|m
  #pragma unroll
  for (int j = 0; j < KK; ++j) lst[j] = ~0ull;

  int rotr = orow & 31;                         // per-row word rotation
  size_t bbase = (size_t)(b * NN) * 64;

  for (int mt = 0; mt < 32; ++mt) {
    int gm0 = gc0 + (mt << 6);
    __syncthreads();  // (a) prev cand consumed + prev Rb reads done
    #pragma unroll
    for (int lvl = 0; lvl < 3; ++lvl) {
      const unsigned short* src = (lvl == 0) ? xThi : (lvl == 1) ? xTmid : xTlo;
      unsigned short* dst = Rb + lvl * 4096;
      #pragma unroll
      for (int p = 0; p < 2; ++p) {
        int idx = p * 256 + t;
        int n = idx >> 3, o = idx & 7;
        *(short8x*)&dst[n * 64 + ((o + n) & 7) * 8] =
            *(const short8x*)&src[bbase + (size_t)(gm0 + n) * 64 + o * 8];
      }
    }
    if (t < 16) *(float4*)&xxs[t * 4] = *(const float4*)&xxg[b * NN + gm0 + t * 4];
    __syncthreads();  // (b) Rb ready

    float4x acc[4];
    #pragma unroll
    for (int j = 0; j < 4; ++j) acc[j] = (float4x){0.f, 0.f, 0.f, 0.f};

    const unsigned short* RbH = Rb;
    const unsigned short* RbM = Rb + 4096;
    const unsigned short* RbL = Rb + 8192;
    #pragma unroll
    for (int ks = 0; ks < 2; ++ks) {
      #pragma unroll
      for (int j = 0; j < 4; ++j) {
        int n = 16 * j + lm;
        int off = n * 64 + ((ks * 4 + quad + n) & 7) * 8;
        short8x bh = *(const short8x*)&RbH[off];
        short8x bm = *(const short8x*)&RbM[off];
        short8x bl = *(const short8x*)&RbL[off];
        acc[j] = __builtin_amdgcn_mfma_f32_16x16x32_bf16(Am[ks], bm, acc[j], 0, 0, 0);
        acc[j] = __builtin_amdgcn_mfma_f32_16x16x32_bf16(Ah[ks], bl, acc[j], 0, 0, 0);
        acc[j] = __builtin_amdgcn_mfma_f32_16x16x32_bf16(Al[ks], bh, acc[j], 0, 0, 0);
        acc[j] = __builtin_amdgcn_mfma_f32_16x16x32_bf16(Ah[ks], bm, acc[j], 0, 0, 0);
        acc[j] = __builtin_amdgcn_mfma_f32_16x16x32_bf16(Am[ks], bh, acc[j], 0, 0, 0);
        acc[j] = __builtin_amdgcn_mfma_f32_16x16x32_bf16(Ah[ks], bh, acc[j], 0, 0, 0);
      }
    }

    float xq[4];
    #pragma unroll
    for (int j = 0; j < 4; ++j) xq[j] = xxs[16 * j + lm];

    __syncthreads();  // (c) Rb reads done -> overwrite as candU

    // keys: xx[m] - 2*G; D layout: col=16j+lm, row=quad*4+q (+16w)
    #pragma unroll
    for (int j = 0; j < 4; ++j) {
      int c = 16 * j + lm;
      #pragma unroll
      for (int q = 0; q < 4; ++q) {
        int rl = quad * 4 + q;
        int r = 16 * w + rl;
        float key = fmaf(-2.f, acc[j][q], xq[j]);
        int pos = (c & 32) | ((c + (r & 31)) & 31);
        candU[r * 64 + pos] = flipf(key);
      }
    }
    __syncthreads();  // (d) cand ready

    // owner scan: 16 cols, conflict-free b32 reads, mask+ctz inserts
    unsigned rc0 = cutq[orow * 4 + 0], rc1 = cutq[orow * 4 + 1];
    unsigned rc2 = cutq[orow * 4 + 2], rc3 = cutq[orow * 4 + 3];
    unsigned thr = min(min(rc0, rc1), min(rc2, rc3));
    unsigned own19 = (unsigned)(lst[KK - 1] >> 12);
    thr = min(thr, own19);
    unsigned mask = 0;
    #pragma unroll
    for (int g = 0; g < 16; ++g) {
      int c = oq * 16 + g;
      int pos = (c & 32) | ((c + rotr) & 31);
      unsigned ku = candU[orow * 64 + pos];
      mask |= (unsigned)(ku <= thr) << g;
    }
    while (mask) {
      int e = __builtin_ctz(mask);
      mask &= mask - 1;
      int c = oq * 16 + e;
      int pos = (c & 32) | ((c + rotr) & 31);
      unsigned ku = candU[orow * 64 + pos];
      unsigned long long p = ((unsigned long long)ku << 12) | (unsigned)(gm0 + c);
      if (p < lst[KK - 1]) {
        #pragma unroll
        for (int j = KK - 1; j >= 1; --j) {
          bool sh = p < lst[j - 1];
          unsigned long long cur = (p < lst[j]) ? p : lst[j];
          lst[j] = sh ? lst[j - 1] : cur;
        }
        if (p < lst[0]) lst[0] = p;
      }
    }
    cutq[orow * 4 + oq] = (unsigned)(lst[KK - 1] >> 12);  // monotone benign race
  }

  // two-phase merge (rows 0-31, then 32-63): M = u64[32][84] aliases Rb
  unsigned long long* M = (unsigned long long*)Rb;
  #pragma unroll 1
  for (int ph = 0; ph < 2; ++ph) {
    __syncthreads();
    if ((orow >> 5) == ph) {
      int r5 = orow & 31;
      #pragma unroll
      for (int k = 0; k < KK; ++k) M[r5 * 84 + oq * 21 + k] = lst[k];
      M[r5 * 84 + oq * 21 + KK] = ~0ull;
    }
    __syncthreads();
    if (t < 32) {
      int h0 = 0, h1 = 0, h2 = 0, h3 = 0;
      int rb = t * 84;
      int row = ph * 32 + t;
      size_t base = ((size_t)(b * NN + gr0 + row) * 2 + half) * KK;
      for (int k = 0; k < KK; ++k) {
        unsigned long long v0 = M[rb + h0];
        unsigned long long v1 = M[rb + 21 + h1];
        unsigned long long v2 = M[rb + 42 + h2];
        unsigned long long v3 = M[rb + 63 + h3];
        unsigned long long bv = v0; int bq = 0;
        if (v1 < bv) { bv = v1; bq = 1; }
        if (v2 < bv) { bv = v2; bq = 2; }
        if (v3 < bv) { bv = v3; bq = 3; }
        keyuG[base + k] = (unsigned)(bv >> 12);
        idxG[base + k] = (unsigned short)(bv & 0xFFFu);
        if (bq == 0) h0++; else if (bq == 1) h1++; else if (bq == 2) h2++; else h3++;
      }
    }
  }
}

__global__ __launch_bounds__(256) void k3_out(const float* __restrict__ y1,
    const float* __restrict__ y2, const unsigned* __restrict__ keyuG,
    const unsigned short* __restrict__ idxG,
    const float* __restrict__ gamma, const float* __restrict__ beta,
    const float* __restrict__ rmean, const float* __restrict__ rvar,
    float* __restrict__ out) {
  __shared__ int sidx[64 * KK];
  __shared__ float ot[64 * 65];  // [o][n], pad 65
  int t = threadIdx.x;
  int b = blockIdx.x >> 6;
  int gr0 = (blockIdx.x & 63) << 6;
  if (t < 64) {  // 2-way merge of column-half lists
    size_t base0 = ((size_t)(b * NN + gr0 + t) * 2) * KK;
    size_t base1 = base0 + KK;
    int h0 = 0, h1 = 0;
    for (int k = 0; k < KK; ++k) {
      int a0 = h0 < KK ? h0 : KK - 1;
      int a1 = h1 < KK ? h1 : KK - 1;
      unsigned k0v = keyuG[base0 + a0]; unsigned i0 = idxG[base0 + a0];
      unsigned k1v = keyuG[base1 + a1]; unsigned i1 = idxG[base1 + a1];
      bool take0 = (h1 >= KK) ||
                   ((h0 < KK) && (k0v < k1v || (k0v == k1v && i0 < i1)));
      sidx[t * KK + k] = take0 ? (int)i0 : (int)i1;
      if (take0) h0++; else h1++;
    }
  }
  int l = t & 63, w = t >> 6;
  float sc = gamma[l] * rsqrtf(rvar[l] + EPSV);
  float tt = fmaf(-rmean[l], sc, beta[l]);
  __syncthreads();
  const float* y2b = y2 + (size_t)b * NN * NO;
  for (int rr = 0; rr < 16; ++rr) {
    int row = w * 16 + rr;
    float v1 = y1[((size_t)b * NN + gr0 + row) * NO + l];
    int mk[KK];
    #pragma unroll
    for (int k = 0; k < KK; ++k) mk[k] = sidx[row * KK + k];
    float vv[KK];
    #pragma unroll
    for (int k = 0; k < KK; ++k) vv[k] = y2b[(size_t)mk[k] * NO + l];  // 20 in flight
    float best = -3.4e38f;
    #pragma unroll
    for (int k = 0; k < KK; ++k) {
      float v = v1 + vv[k];
      v = fmaf(v, sc, tt);
      v = v >= 0.f ? v : SLOPE * v;
      best = fmaxf(best, v);
    }
    ot[l * 65 + row] = best;
  }
  __syncthreads();
  float* ob = out + (size_t)b * NO * NN;
  for (int i = t; i < 4096; i += 256) {
    int o = i >> 6, n = i & 63;
    ob[(size_t)o * NN + gr0 + n] = ot[o * 65 + n];  // coalesced
  }
}

extern "C" void kernel_launch(void* const* d_in, const int* in_sizes, int n_in,
                              void* d_out, int out_size, void* d_ws, size_t ws_size,
                              hipStream_t stream) {
  const float* x     = (const float*)d_in[0];
  const float* W     = (const float*)d_in[1];
  const float* gamma = (const float*)d_in[2];
  const float* beta  = (const float*)d_in[3];
  const float* rmean = (const float*)d_in[4];
  const float* rvar  = (const float*)d_in[5];
  float* ws  = (float*)d_ws;
  float* y1    = ws;
  float* y2    = ws + 2097152;
  float* xx    = ws + 4194304;
  unsigned* keyu = (unsigned*)(ws + 4227072);
  unsigned short* idxu = (unsigned short*)(ws + 5537792);
  float* wa    = ws + 6193152;
  float* wb    = ws + 6197248;
  unsigned short* xThi  = (unsigned short*)(ws + 6201344);
  unsigned short* xTmid = (unsigned short*)(ws + 7249920);
  unsigned short* xTlo  = (unsigned short*)(ws + 8298496);
  float* out = (float*)d_out;

  hipLaunchKernelGGL(k0_wprep, dim3(1),    dim3(256), 0, stream, W, wa, wb);
  hipLaunchKernelGGL(k1_feat,  dim3(512),  dim3(256), 0, stream, x, wa, wb, y1, y2, xx,
                     xThi, xTmid, xTlo);
  hipLaunchKernelGGL(k2_topk,  dim3(1024), dim3(256), 0, stream, xThi, xTmid, xTlo,
                     xx, keyu, idxu);
  hipLaunchKernelGGL(k3_out,   dim3(512),  dim3(256), 0, stream, y1, y2, keyu, idxu,
                     gamma, beta, rmean, rvar, out);
}

// Round 12
// 403.640 us; speedup vs baseline: 1.5432x; 1.0000x over previous
//
#include <hip/hip_runtime.h>

#define NB 8
#define NC 64
#define NN 4096
#define NO 64
#define KK 20
#define EPSV 1e-5f
#define SLOPE 0.2f

typedef __attribute__((ext_vector_type(8))) short short8x;
typedef __attribute__((ext_vector_type(4))) float float4x;

// ws layout (float words):
// y1   : [B][N][O]            @0         2097152
// y2   : [B][N][O]            @2097152   2097152
// xx   : [B][N]               @4194304   32768
// keyu : [B][N][2][20] u32    @4227072   1310720
// idxu : [B][N][2][20] u16    @5537792   655360 words
// wa   : [C][O]               @6193152   4096
// wb   : [C][O]               @6197248   4096
// xThi : [B][N][C] bf16       @6201344   1048576
// xTmid: [B][N][C] bf16       @7249920   1048576
// xTlo : [B][N][C] bf16       @8298496   1048576

__device__ __forceinline__ unsigned short bfh(float f) {  // fp32 -> bf16 (RNE)
  unsigned u = __float_as_uint(f);
  unsigned r = u + 0x7FFFu + ((u >> 16) & 1u);
  return (unsigned short)(r >> 16);
}

__device__ __forceinline__ unsigned flipf(float f) {
  unsigned u = __float_as_uint(f);
  return u ^ ((unsigned)((int)u >> 31) | 0x80000000u);
}

__global__ void k0_wprep(const float* __restrict__ W,
                         float* __restrict__ wa, float* __restrict__ wb) {
  int t = threadIdx.x;
  for (int i = t; i < NC * NO; i += 256) {
    int o = i & 63, c = i >> 6;
    float w1 = W[o * 128 + c];
    float w2 = W[o * 128 + 64 + c];
    wa[i] = w1 - w2;  // [c][o]
    wb[i] = w2;
  }
}

__global__ __launch_bounds__(256) void k1_feat(const float* __restrict__ x,
    const float* __restrict__ waT, const float* __restrict__ wbT,
    float* __restrict__ y1, float* __restrict__ y2, float* __restrict__ xxg,
    unsigned short* __restrict__ xThi, unsigned short* __restrict__ xTmid,
    unsigned short* __restrict__ xTlo) {
  __shared__ __align__(16) float xs[NC * 68];   // [c][n] stride 68
  __shared__ __align__(16) float wa[NC * NO];
  __shared__ __align__(16) float wb[NC * NO];
  int t = threadIdx.x;
  int b = blockIdx.x >> 6;
  int gr0 = (blockIdx.x & 63) << 6;
  const float* xb = x + (size_t)b * NC * NN;
  #pragma unroll
  for (int k = 0; k < 4; ++k) {
    int i4 = t + k * 256;
    int c = i4 >> 4, col4 = (i4 & 15) << 2;
    *(float4*)&xs[c * 68 + col4] = *(const float4*)&xb[(size_t)c * NN + gr0 + col4];
    *(float4*)&wa[c * 64 + col4] = *(const float4*)&waT[c * 64 + col4];
    *(float4*)&wb[c * 64 + col4] = *(const float4*)&wbT[c * 64 + col4];
  }
  __syncthreads();
  if (t < 64) {
    float s = 0.f;
    #pragma unroll
    for (int c = 0; c < NC; ++c) { float v = xs[c * 68 + t]; s = fmaf(v, v, s); }
    xxg[b * NN + gr0 + t] = s;
  }
  int o = t & 63, w = t >> 6;
  for (int j = 0; j < 16; ++j) {
    int n = j * 4 + w;
    float a1 = 0.f, a2 = 0.f;
    #pragma unroll
    for (int c = 0; c < NC; ++c) {
      float xv = xs[c * 68 + n];
      a1 = fmaf(wa[c * 64 + o], xv, a1);
      a2 = fmaf(wb[c * 64 + o], xv, a2);
    }
    size_t base = ((size_t)b * NN + gr0 + n) * NO + o;
    y1[base] = a1;
    y2[base] = a2;
  }
  // 3-level bf16 split (REQUIRED: 2-level flips top-K selections, R10 failed),
  // transposed layout xT[b][n][c]
  int n2 = t >> 2, c0 = (t & 3) << 4;
  short8x vh[2], vm[2], vl[2];
  #pragma unroll
  for (int i = 0; i < 16; ++i) {
    float v = xs[(c0 + i) * 68 + n2];
    unsigned short h = bfh(v);
    float hf = __uint_as_float((unsigned)h << 16);
    float r1 = v - hf;
    unsigned short md = bfh(r1);
    float mf = __uint_as_float((unsigned)md << 16);
    unsigned short lo = bfh(r1 - mf);
    vh[i >> 3][i & 7] = (short)h;
    vm[i >> 3][i & 7] = (short)md;
    vl[i >> 3][i & 7] = (short)lo;
  }
  size_t tb = ((size_t)(b * NN + gr0 + n2)) * 64 + c0;
  *(short8x*)&xThi[tb] = vh[0];  *(short8x*)&xThi[tb + 8] = vh[1];
  *(short8x*)&xTmid[tb] = vm[0]; *(short8x*)&xTmid[tb + 8] = vm[1];
  *(short8x*)&xTlo[tb] = vl[0];  *(short8x*)&xTlo[tb + 8] = vl[1];
}

// ----- MFMA split-bf16 Gram + per-row exact top-K (column half) -----
// grid 1024: blk = b*128 + rowgroup*2 + half (R7-proven ordering, 34MB fetch)
// __launch_bounds__(256,3): cap ~170 VGPR -- lst[20] u64 MUST stay in regs
// (R8/R9 lesson: (256,5) cap 102 spilled lst to scratch -> 0.8GB HBM traffic)
// candU in its OWN LDS (no Rb alias) -> 3 barriers/tile instead of 4;
// LDS 42.2KB -> 3 blocks/CU co-resident.
__global__ __launch_bounds__(256, 3) void k2_topk(
    const unsigned short* __restrict__ xThi, const unsigned short* __restrict__ xTmid,
    const unsigned short* __restrict__ xTlo, const float* __restrict__ xxg,
    unsigned* __restrict__ keyuG, unsigned short* __restrict__ idxG) {
  __shared__ __align__(16) unsigned short Rb[3 * 4096];  // 24KB staging hi/mid/lo;
                                                         // merge M u64[32*84]=21.5KB aliases
  __shared__ __align__(16) unsigned candU[4096];         // 16KB key transpose buffer
  __shared__ __align__(16) float xxs[64];
  __shared__ unsigned cutq[256];                         // [r][q], flipped-u32

  int t = threadIdx.x;
  int blk = blockIdx.x;
  int b = blk >> 7;
  int rem = blk & 127;
  int rg = rem >> 1, half = rem & 1;
  int gr0 = rg << 6;
  int gc0 = half << 11;
  int w = t >> 6;                               // wave: rows 16w..16w+15
  int lm = t & 15;                              // lane&15
  int quad = (t >> 4) & 3;                      // lane>>4
  int orow = t & 63, oq = t >> 6;               // owner (row, quarter)

  // persistent A-fragments (rows gr0+16w+lm, 3 levels x 2 k-steps)
  size_t abase = ((size_t)(b * NN + gr0 + 16 * w + lm)) * 64;
  short8x Ah[2], Am[2], Al[2];
  #pragma unroll
  for (int ks = 0; ks < 2; ++ks) {
    int co = ks * 32 + quad * 8;
    Ah[ks] = *(const short8x*)&xThi[abase + co];
    Am[ks] = *(const short8x*)&xTmid[abase + co];
    Al[ks] = *(const short8x*)&xTlo[abase + co];
  }
  cutq[t] = 0xFFFFFFFFu;

  unsigned long long lst[KK];                   // packed (flip(key)<<12)|m
  #pragma unroll
  for (int j = 0; j < KK; ++j) lst[j] = ~0ull;

  int rotr = orow & 31;                         // per-row word rotation
  size_t bbase = (size_t)(b * NN) * 64;

  for (int mt = 0; mt < 32; ++mt) {
    int gm0 = gc0 + (mt << 6);
    __syncthreads();  // (A) prev owner scan done (candU free) + prev MFMA reads done (Rb free)
    #pragma unroll
    for (int lvl = 0; lvl < 3; ++lvl) {
      const unsigned short* src = (lvl == 0) ? xThi : (lvl == 1) ? xTmid : xTlo;
      unsigned short* dst = Rb + lvl * 4096;
      #pragma unroll
      for (int p = 0; p < 2; ++p) {
        int idx = p * 256 + t;
        int n = idx >> 3, o = idx & 7;
        *(short8x*)&dst[n * 64 + ((o + n) & 7) * 8] =
            *(const short8x*)&src[bbase + (size_t)(gm0 + n) * 64 + o * 8];
      }
    }
    if (t < 16) *(float4*)&xxs[t * 4] = *(const float4*)&xxg[b * NN + gm0 + t * 4];
    __syncthreads();  // (B) Rb ready

    float4x acc[4];
    #pragma unroll
    for (int j = 0; j < 4; ++j) acc[j] = (float4x){0.f, 0.f, 0.f, 0.f};

    const unsigned short* RbH = Rb;
    const unsigned short* RbM = Rb + 4096;
    const unsigned short* RbL = Rb + 8192;
    #pragma unroll
    for (int ks = 0; ks < 2; ++ks) {
      #pragma unroll
      for (int j = 0; j < 4; ++j) {
        int n = 16 * j + lm;
        int off = n * 64 + ((ks * 4 + quad + n) & 7) * 8;
        short8x bh = *(const short8x*)&RbH[off];
        short8x bm = *(const short8x*)&RbM[off];
        short8x bl = *(const short8x*)&RbL[off];
        acc[j] = __builtin_amdgcn_mfma_f32_16x16x32_bf16(Am[ks], bm, acc[j], 0, 0, 0);
        acc[j] = __builtin_amdgcn_mfma_f32_16x16x32_bf16(Ah[ks], bl, acc[j], 0, 0, 0);
        acc[j] = __builtin_amdgcn_mfma_f32_16x16x32_bf16(Al[ks], bh, acc[j], 0, 0, 0);
        acc[j] = __builtin_amdgcn_mfma_f32_16x16x32_bf16(Ah[ks], bm, acc[j], 0, 0, 0);
        acc[j] = __builtin_amdgcn_mfma_f32_16x16x32_bf16(Am[ks], bh, acc[j], 0, 0, 0);
        acc[j] = __builtin_amdgcn_mfma_f32_16x16x32_bf16(Ah[ks], bh, acc[j], 0, 0, 0);
      }
    }

    float xq[4];
    #pragma unroll
    for (int j = 0; j < 4; ++j) xq[j] = xxs[16 * j + lm];

    // keys: xx[m] - 2*G; D layout: col=16j+lm, row=quad*4+q (+16w)
    // candU is separate memory -> no barrier needed between MFMA and these writes
    #pragma unroll
    for (int j = 0; j < 4; ++j) {
      int c = 16 * j + lm;
      #pragma unroll
      for (int q = 0; q < 4; ++q) {
        int rl = quad * 4 + q;
        int r = 16 * w + rl;
        float key = fmaf(-2.f, acc[j][q], xq[j]);
        int pos = (c & 32) | ((c + (r & 31)) & 31);
        candU[r * 64 + pos] = flipf(key);
      }
    }
    __syncthreads();  // (C) cand ready

    // owner scan: 16 cols, conflict-free b32 reads, mask+ctz inserts
    unsigned rc0 = cutq[orow * 4 + 0], rc1 = cutq[orow * 4 + 1];
    unsigned rc2 = cutq[orow * 4 + 2], rc3 = cutq[orow * 4 + 3];
    unsigned thr = min(min(rc0, rc1), min(rc2, rc3));
    unsigned own19 = (unsigned)(lst[KK - 1] >> 12);
    thr = min(thr, own19);
    unsigned mask = 0;
    #pragma unroll
    for (int g = 0; g < 16; ++g) {
      int c = oq * 16 + g;
      int pos = (c & 32) | ((c + rotr) & 31);
      unsigned ku = candU[orow * 64 + pos];
      mask |= (unsigned)(ku <= thr) << g;
    }
    while (mask) {
      int e = __builtin_ctz(mask);
      mask &= mask - 1;
      int c = oq * 16 + e;
      int pos = (c & 32) | ((c + rotr) & 31);
      unsigned ku = candU[orow * 64 + pos];
      unsigned long long p = ((unsigned long long)ku << 12) | (unsigned)(gm0 + c);
      if (p < lst[KK - 1]) {
        #pragma unroll
        for (int j = KK - 1; j >= 1; --j) {
          bool sh = p < lst[j - 1];
          unsigned long long cur = (p < lst[j]) ? p : lst[j];
          lst[j] = sh ? lst[j - 1] : cur;
        }
        if (p < lst[0]) lst[0] = p;
      }
    }
    cutq[orow * 4 + oq] = (unsigned)(lst[KK - 1] >> 12);  // monotone benign race
  }

  // two-phase merge (rows 0-31, then 32-63): M = u64[32][84] aliases Rb (dead now)
  unsigned long long* M = (unsigned long long*)Rb;
  #pragma unroll 1
  for (int ph = 0; ph < 2; ++ph) {
    __syncthreads();
    if ((orow >> 5) == ph) {
      int r5 = orow & 31;
      #pragma unroll
      for (int k = 0; k < KK; ++k) M[r5 * 84 + oq * 21 + k] = lst[k];
      M[r5 * 84 + oq * 21 + KK] = ~0ull;
    }
    __syncthreads();
    if (t < 32) {
      int h0 = 0, h1 = 0, h2 = 0, h3 = 0;
      int rb = t * 84;
      int row = ph * 32 + t;
      size_t base = ((size_t)(b * NN + gr0 + row) * 2 + half) * KK;
      for (int k = 0; k < KK; ++k) {
        unsigned long long v0 = M[rb + h0];
        unsigned long long v1 = M[rb + 21 + h1];
        unsigned long long v2 = M[rb + 42 + h2];
        unsigned long long v3 = M[rb + 63 + h3];
        unsigned long long bv = v0; int bq = 0;
        if (v1 < bv) { bv = v1; bq = 1; }
        if (v2 < bv) { bv = v2; bq = 2; }
        if (v3 < bv) { bv = v3; bq = 3; }
        keyuG[base + k] = (unsigned)(bv >> 12);
        idxG[base + k] = (unsigned short)(bv & 0xFFFu);
        if (bq == 0) h0++; else if (bq == 1) h1++; else if (bq == 2) h2++; else h3++;
      }
    }
  }
}

__global__ __launch_bounds__(256) void k3_out(const float* __restrict__ y1,
    const float* __restrict__ y2, const unsigned* __restrict__ keyuG,
    const unsigned short* __restrict__ idxG,
    const float* __restrict__ gamma, const float* __restrict__ beta,
    const float* __restrict__ rmean, const float* __restrict__ rvar,
    float* __restrict__ out) {
  __shared__ int sidx[64 * KK];
  __shared__ float ot[64 * 65];  // [o][n], pad 65
  int t = threadIdx.x;
  int b = blockIdx.x >> 6;
  int gr0 = (blockIdx.x & 63) << 6;
  if (t < 64) {  // 2-way merge of column-half lists
    size_t base0 = ((size_t)(b * NN + gr0 + t) * 2) * KK;
    size_t base1 = base0 + KK;
    int h0 = 0, h1 = 0;
    for (int k = 0; k < KK; ++k) {
      int a0 = h0 < KK ? h0 : KK - 1;
      int a1 = h1 < KK ? h1 : KK - 1;
      unsigned k0v = keyuG[base0 + a0]; unsigned i0 = idxG[base0 + a0];
      unsigned k1v = keyuG[base1 + a1]; unsigned i1 = idxG[base1 + a1];
      bool take0 = (h1 >= KK) ||
                   ((h0 < KK) && (k0v < k1v || (k0v == k1v && i0 < i1)));
      sidx[t * KK + k] = take0 ? (int)i0 : (int)i1;
      if (take0) h0++; else h1++;
    }
  }
  int l = t & 63, w = t >> 6;
  float sc = gamma[l] * rsqrtf(rvar[l] + EPSV);
  float tt = fmaf(-rmean[l], sc, beta[l]);
  __syncthreads();
  const float* y2b = y2 + (size_t)b * NN * NO;
  for (int rr = 0; rr < 16; ++rr) {
    int row = w * 16 + rr;
    float v1 = y1[((size_t)b * NN + gr0 + row) * NO + l];
    int mk[KK];
    #pragma unroll
    for (int k = 0; k < KK; ++k) mk[k] = sidx[row * KK + k];
    float vv[KK];
    #pragma unroll
    for (int k = 0; k < KK; ++k) vv[k] = y2b[(size_t)mk[k] * NO + l];  // 20 in flight
    float best = -3.4e38f;
    #pragma unroll
    for (int k = 0; k < KK; ++k) {
      float v = v1 + vv[k];
      v = fmaf(v, sc, tt);
      v = v >= 0.f ? v : SLOPE * v;
      best = fmaxf(best, v);
    }
    ot[l * 65 + row] = best;
  }
  __syncthreads();
  float* ob = out + (size_t)b * NO * NN;
  for (int i = t; i < 4096; i += 256) {
    int o = i >> 6, n = i & 63;
    ob[(size_t)o * NN + gr0 + n] = ot[o * 65 + n];  // coalesced
  }
}

extern "C" void kernel_launch(void* const* d_in, const int* in_sizes, int n_in,
                              void* d_out, int out_size, void* d_ws, size_t ws_size,
                              hipStream_t stream) {
  const float* x     = (const float*)d_in[0];
  const float* W     = (const float*)d_in[1];
  const float* gamma = (const float*)d_in[2];
  const float* beta  = (const float*)d_in[3];
  const float* rmean = (const float*)d_in[4];
  const float* rvar  = (const float*)d_in[5];
  float* ws  = (float*)d_ws;
  float* y1    = ws;
  float* y2    = ws + 2097152;
  float* xx    = ws + 4194304;
  unsigned* keyu = (unsigned*)(ws + 4227072);
  unsigned short* idxu = (unsigned short*)(ws + 5537792);
  float* wa    = ws + 6193152;
  float* wb    = ws + 6197248;
  unsigned short* xThi  = (unsigned short*)(ws + 6201344);
  unsigned short* xTmid = (unsigned short*)(ws + 7249920);
  unsigned short* xTlo  = (unsigned short*)(ws + 8298496);
  float* out = (float*)d_out;

  hipLaunchKernelGGL(k0_wprep, dim3(1),    dim3(256), 0, stream, W, wa, wb);
  hipLaunchKernelGGL(k1_feat,  dim3(512),  dim3(256), 0, stream, x, wa, wb, y1, y2, xx,
                     xThi, xTmid, xTlo);
  hipLaunchKernelGGL(k2_topk,  dim3(1024), dim3(256), 0, stream, xThi, xTmid, xTlo,
                     xx, keyu, idxu);
  hipLaunchKernelGGL(k3_out,   dim3(512),  dim3(256), 0, stream, y1, y2, keyu, idxu,
                     gamma, beta, rmean, rvar, out);
}